// Round 1
// baseline (493.660 us; speedup 1.0000x reference)
//
#include <hip/hip_runtime.h>

// StereoCostVolume: c1, warp [B=8, H=192, W=640, C=64] f32.
// out [B,H,W,69]: out[...,0:64] = c1; out[...,64+d] = mean_c(c1 * warp shifted by d-2 along W, zero pad).
//
// One wave (64 lanes) per output pixel: lane = channel. All global accesses are
// coalesced 256B wave transactions. 5 dot products via __shfl_xor butterfly.

#define BDIM 256
#define WIDTH 640
#define CH 64
#define NOFF 5
#define TOTAL_PIX (8 * 192 * 640)

__global__ __launch_bounds__(BDIM) void StereoCostVolume_kernel(
    const float* __restrict__ c1,
    const float* __restrict__ warp,
    float* __restrict__ out)
{
    const int gid  = blockIdx.x * BDIM + threadIdx.x;
    const int pix  = gid >> 6;          // wave index = pixel index
    const int lane = threadIdx.x & 63;  // channel
    if (pix >= TOTAL_PIX) return;

    const int w = pix % WIDTH;

    const int ibase = pix * CH;         // < 2^26, int is fine
    const int obase = pix * (CH + NOFF);

    const float a = c1[ibase + lane];
    out[obase + lane] = a;              // passthrough, coalesced 256B

    float s0, s1, s2, s3, s4;
    #pragma unroll
    for (int d = 0; d < NOFF; ++d) {
        const int ww = w + d - 2;
        float b = 0.0f;
        if (ww >= 0 && ww < WIDTH)
            b = warp[ibase + (d - 2) * CH + lane];   // coalesced; L1/L2 absorbs 5x reuse
        float p = a * b;
        // full-wave butterfly sum (64 lanes)
        #pragma unroll
        for (int m = 32; m >= 1; m >>= 1)
            p += __shfl_xor(p, m, 64);
        if (d == 0) s0 = p;
        else if (d == 1) s1 = p;
        else if (d == 2) s2 = p;
        else if (d == 3) s3 = p;
        else s4 = p;
    }

    if (lane < NOFF) {
        float v = (lane == 0) ? s0 : (lane == 1) ? s1 : (lane == 2) ? s2
                : (lane == 3) ? s3 : s4;
        out[obase + CH + lane] = v * (1.0f / 64.0f);
    }
}

extern "C" void kernel_launch(void* const* d_in, const int* in_sizes, int n_in,
                              void* d_out, int out_size, void* d_ws, size_t ws_size,
                              hipStream_t stream) {
    const float* c1   = (const float*)d_in[0];
    const float* warp = (const float*)d_in[1];
    // d_in[2] = search_range (int scalar) — fixed at 2; output shape bakes it in.
    float* out = (float*)d_out;

    const int total_waves  = TOTAL_PIX;            // one wave per pixel
    const int waves_per_blk = BDIM / 64;
    const int grid = (total_waves + waves_per_blk - 1) / waves_per_blk;

    StereoCostVolume_kernel<<<grid, BDIM, 0, stream>>>(c1, warp, out);
}

// Round 3
// 145.608 us; speedup vs baseline: 3.3903x; 3.3903x over previous
//
#include <hip/hip_runtime.h>

// StereoCostVolume: c1, warp [B=8, H=192, W=640, C=64] f32.
// out [B,H,W,69]: out[...,0:64] = c1; out[...,64+d] = mean_c(c1[w] * warp[w+d-2]), zero-padded in W.
//
// Block = 512 threads handles a 64-pixel row tile.
// Thread t: chan4 = t&15 (4 channels), pixels {t>>4, (t>>4)+32}.
// - warp tile (68 px) staged linearly to LDS (coalesced float4).
// - c1 read directly to registers (coalesced: each wave reads contiguous 1KB).
// - partial dots (4ch) reduced across 16 lanes via DPP row_shl adds (VALU pipe, no DS);
//   row_shl pulls from lane i+N, so the FULL sum lands in lane 0 of each 16-lane row.
// - output tile assembled in reused LDS, stored as linear 16B-aligned float4 stream.

#define WIDTH 640
#define CH 64
#define NOFF 5
#define OUTC 69
#define TILE_PIX 64
#define BDIM 512
#define TILES_PER_ROW (WIDTH / TILE_PIX)      // 10
#define NROWS (8 * 192)                       // 1536
#define WARP_F4 ((TILE_PIX + 4) * (CH / 4))   // 68 px * 16 = 1088 float4
#define OUT_F4 (TILE_PIX * OUTC / 4)          // 1104 float4

__device__ __forceinline__ float row_reduce_sum16_lane0(float v) {
    union { float f; int i; } a, b;
    a.f = v;
    // row_shl:N = dpp_ctrl 0x100+N: lane i reads lane i+N (invalid -> 0 with bound_ctrl).
    b.i = __builtin_amdgcn_update_dpp(0, a.i, 0x101, 0xF, 0xF, true); a.f += b.f;
    b.i = __builtin_amdgcn_update_dpp(0, a.i, 0x102, 0xF, 0xF, true); a.f += b.f;
    b.i = __builtin_amdgcn_update_dpp(0, a.i, 0x104, 0xF, 0xF, true); a.f += b.f;
    b.i = __builtin_amdgcn_update_dpp(0, a.i, 0x108, 0xF, 0xF, true); a.f += b.f;
    return a.f;  // lane 0 of each 16-lane row holds the full 16-lane sum
}

__global__ __launch_bounds__(BDIM) void StereoCostVolume_kernel(
    const float* __restrict__ c1,
    const float* __restrict__ warp,
    float* __restrict__ out)
{
    __shared__ float4 lds[OUT_F4];   // 17664 B; warp tile first, then reused as out tile

    const int t   = threadIdx.x;
    const int bx  = blockIdx.x;
    const int tw  = bx % TILES_PER_ROW;
    const int row = bx / TILES_PER_ROW;          // b*H + h
    const int w0  = tw * TILE_PIX;
    const int pix0 = row * WIDTH + w0;           // global pixel index of tile start

    const float4* c1f4   = (const float4*)c1;
    const float4* warpf4 = (const float4*)warp;

    const int c4 = t & 15;      // chan4 group
    const int p0 = t >> 4;      // local pixel [0,32); also handles p0+32

    // c1 for this thread's 2 pixels (coalesced: wave reads contiguous 1KB)
    const float4 a0 = c1f4[(pix0 + p0) * 16 + c4];
    const float4 a1 = c1f4[(pix0 + p0 + 32) * 16 + c4];

    // ---- stage warp tile [w0-2, w0+66) into LDS, zero-padded at row edges ----
    {
        float4 v[3];
        #pragma unroll
        for (int r = 0; r < 3; ++r) {
            const int idx = t + r * BDIM;
            v[r] = make_float4(0.f, 0.f, 0.f, 0.f);
            if (idx < WARP_F4) {
                const int wp = w0 - 2 + (idx >> 4);          // width coordinate
                if (wp >= 0 && wp < WIDTH)
                    v[r] = warpf4[(row * WIDTH + wp) * 16 + (idx & 15)];
            }
        }
        #pragma unroll
        for (int r = 0; r < 3; ++r) {
            const int idx = t + r * BDIM;
            if (idx < WARP_F4) lds[idx] = v[r];
        }
    }
    __syncthreads();

    // ---- compute 5 correlation partials per pixel, reduce over 16 lanes ----
    float s[2][NOFF];
    #pragma unroll
    for (int j = 0; j < 2; ++j) {
        const int p = p0 + 32 * j;
        const float4 a = (j == 0) ? a0 : a1;
        #pragma unroll
        for (int d = 0; d < NOFF; ++d) {
            const float4 b = lds[(p + d) * 16 + c4];   // warp tile pixel p+d == w + d - 2
            const float acc = a.x * b.x + a.y * b.y + a.z * b.z + a.w * b.w;
            s[j][d] = row_reduce_sum16_lane0(acc);
        }
    }
    __syncthreads();   // warp tile dead; LDS becomes out tile

    // ---- assemble output tile in LDS ----
    {
        float* ldsw = (float*)lds;
        #pragma unroll
        for (int j = 0; j < 2; ++j) {
            const int p = p0 + 32 * j;
            const float4 a = (j == 0) ? a0 : a1;
            const int base = p * OUTC + c4 * 4;
            ldsw[base + 0] = a.x;
            ldsw[base + 1] = a.y;
            ldsw[base + 2] = a.z;
            ldsw[base + 3] = a.w;
        }
        if ((t & 15) == 0) {
            #pragma unroll
            for (int j = 0; j < 2; ++j) {
                const int p = p0 + 32 * j;
                #pragma unroll
                for (int d = 0; d < NOFF; ++d)
                    ldsw[p * OUTC + CH + d] = s[j][d] * (1.0f / 64.0f);
            }
        }
    }
    __syncthreads();

    // ---- linear coalesced store of the out tile (16B-aligned: pix0*69*4 % 16 == 0) ----
    {
        float4* outf4 = (float4*)out;
        const int obase = (pix0 * OUTC) >> 2;    // pix0 multiple of 64 -> exact
        #pragma unroll
        for (int r = 0; r < 3; ++r) {
            const int idx = t + r * BDIM;
            if (idx < OUT_F4) outf4[obase + idx] = lds[idx];
        }
    }
}

extern "C" void kernel_launch(void* const* d_in, const int* in_sizes, int n_in,
                              void* d_out, int out_size, void* d_ws, size_t ws_size,
                              hipStream_t stream) {
    const float* c1   = (const float*)d_in[0];
    const float* warp = (const float*)d_in[1];
    float* out = (float*)d_out;

    const int grid = NROWS * TILES_PER_ROW;   // 15360 blocks
    StereoCostVolume_kernel<<<grid, BDIM, 0, stream>>>(c1, warp, out);
}